// Round 14
// baseline (159.152 us; speedup 1.0000x reference)
//
#include <hip/hip_runtime.h>
#include <hip/hip_fp16.h>

typedef _Float16 f16x8 __attribute__((ext_vector_type(8)));
typedef _Float16 f16x4 __attribute__((ext_vector_type(4)));
typedef float    f32x4 __attribute__((ext_vector_type(4)));

#define T_STEPS 32
#define NROWS   10000
#define DDIM    256
#define ROWS_PB 20                     // 500 blocks exactly -> 2 blocks/CU
#define TILE_ROWS 32                   // LDS tile rows (20 real + 12 pad)
#define TILE_B  (TILE_ROWS * 512)      // 16384 B per f16 tile
#define NCHUNK4 (ROWS_PB * DDIM / 4)   // 1280 f32x4 chunks per H slab
#define NCHUNK16 (ROWS_PB * 32)        // 640 16B chunks per S tile (real rows)

// ---------------------------------------------------------------------------
// Pre-kernel: f32 weights -> f16 MFMA B-fragments.
// Fragment (ct,ks), ct=0..15, ks=0..7:
//   dst[((ct*8+ks)*64+lane)*8 + j] = W[ct*16 + (lane&15)][ks*32 + (lane>>4)*8 + j]
// ---------------------------------------------------------------------------
__global__ __launch_bounds__(256) void cvt_weights_kernel(
    const float* __restrict__ Aw, const float* __restrict__ Bw,
    _Float16* __restrict__ wsA, _Float16* __restrict__ wsB)
{
    int tid  = blockIdx.x * 256 + threadIdx.x;      // 0..8191
    int lane = tid & 63;
    int ks   = (tid >> 6) & 7;
    int ct   = tid >> 9;                            // 0..15
    int e     = ct * 16 + (lane & 15);
    int dbase = ks * 32 + (lane >> 4) * 8;
    size_t src = (size_t)e * DDIM + dbase;
    size_t dst = (size_t)tid * 8;
#pragma unroll
    for (int j = 0; j < 8; ++j) {
        wsA[dst + j] = (_Float16)Aw[src + j];
        wsB[dst + j] = (_Float16)Bw[src + j];
    }
}

// Barrier WITHOUT the compiler's vmcnt(0) drain: LDS deps are covered by
// lgkmcnt(0); global stores / prefetch loads keep draining across steps.
__device__ __forceinline__ void barrier_lgkm() {
    asm volatile("s_waitcnt lgkmcnt(0)\n\ts_barrier" ::: "memory");
}

// ---------------------------------------------------------------------------
// Fused SSM — R13 winner's schedule at HALF block size so TWO blocks
// co-reside per CU (64 KB LDS each): one block's K-loop covers the other
// block's staging/scatter/barrier tail (TLP instead of intra-block
// restructuring). 8 waves (512 thr); wave w owns cols [32w,32w+32) =
// 2 col-tiles; weights in registers (128 VGPR/lane); full-step H prefetch
// (single bank); ONE lgkm-only barrier per step; NT hints on stream-once
// traffic; full-128B-line f32 stores from LDS readback.
// ---------------------------------------------------------------------------
__global__ __launch_bounds__(512, 2) void ssm_fused_kernel(
    const float* __restrict__ H,          // [T][N][D] f32
    const _Float16* __restrict__ WaF,     // frag-permuted f16
    const _Float16* __restrict__ WbF,
    const float* __restrict__ bias,       // [D] f32
    float* __restrict__ out)              // [T][N][D] f32
{
    // Hbuf0 | Hbuf1 | Sbuf0 | Sbuf1, each 16 KiB (64 KiB total)
    __shared__ char lds[4 * TILE_B];

    const int tid  = threadIdx.x;
    const int lane = tid & 63;
    const int wc   = tid >> 6;            // 0..7: 32-col strip
    const int lr   = lane & 15;
    const int kg   = lane >> 4;           // 0..3
    const int row0 = blockIdx.x * ROWS_PB;

    // ---- one-time: this wave's weight fragments (2 col-tiles) -> 128 VGPRs
    f16x8 wA[2][8], wB[2][8];
#pragma unroll
    for (int et = 0; et < 2; ++et) {
        const int ct = wc * 2 + et;
#pragma unroll
        for (int ks = 0; ks < 8; ++ks) {
            size_t o = (size_t)((ct * 8 + ks) * 64 + lane) * 8;
            wA[et][ks] = *reinterpret_cast<const f16x8*>(WaF + o);
            wB[et][ks] = *reinterpret_cast<const f16x8*>(WbF + o);
        }
    }

    float bv[2];
#pragma unroll
    for (int et = 0; et < 2; ++et) bv[et] = bias[wc * 32 + et * 16 + lr];

    // Block's H slab at step t: H + t*N*D + row0*D, 5120 floats, contiguous.
    const float* Hslab = H + (size_t)row0 * DDIM;

    // ---- prologue: H_0 -> Hbuf0, then issue H_1 into the (single) bank ----
    // flat chunks: idx in [0,1280); j=2 masked to tid<256.
    f32x4 hreg[3];
#pragma unroll
    for (int j = 0; j < 3; ++j) {
        int idx = j * 512 + tid;
        if (idx < NCHUNK4)
            hreg[j] = __builtin_nontemporal_load(
                reinterpret_cast<const f32x4*>(Hslab + (size_t)idx * 4));
    }
#pragma unroll
    for (int j = 0; j < 3; ++j) {
        int idx = j * 512 + tid;
        if (idx < NCHUNK4) {
            int r = idx >> 6;             // 0..19 (real rows only staged)
            f16x4 v;
#pragma unroll
            for (int k = 0; k < 4; ++k) v[k] = (_Float16)hreg[j][k];
            *reinterpret_cast<f16x4*>(lds + r * 512 + (((idx & 63) * 8) ^ ((r & 7) << 4))) = v;
        }
    }
#pragma unroll
    for (int j = 0; j < 3; ++j) {
        int idx = j * 512 + tid;
        if (idx < NCHUNK4)
            hreg[j] = __builtin_nontemporal_load(
                reinterpret_cast<const f32x4*>(Hslab + (size_t)NROWS * DDIM + (size_t)idx * 4));
    }
    __syncthreads();

    f32x4 acc[2][2];

    for (int t = 0; t < T_STEPS; ++t) {
        const int cur = t & 1;
        char* Hc = lds + cur * TILE_B;
        char* Hn = lds + (cur ^ 1) * TILE_B;
        char* Sc = lds + 2 * TILE_B + cur * TILE_B;
        char* Sn = lds + 2 * TILE_B + (cur ^ 1) * TILE_B;

        // 1. init acc with bias (C/D: col = lane&15)
#pragma unroll
        for (int nt = 0; nt < 2; ++nt)
#pragma unroll
            for (int et = 0; et < 2; ++et)
#pragma unroll
                for (int i = 0; i < 4; ++i) acc[nt][et][i] = bv[et];

        // 2. K-loop: each A-fragment read feeds BOTH col-tiles (2 MFMAs).
        //    Rows 20-31 are pad: junk there only affects pad-row outputs.
        __builtin_amdgcn_s_setprio(1);
#pragma unroll
        for (int ks = 0; ks < 8; ++ks) {
            const int cbyte = ks * 64 + kg * 16;
            f16x8 hfrag[2];
#pragma unroll
            for (int nt = 0; nt < 2; ++nt) {
                int r = nt * 16 + lr;
                hfrag[nt] = *reinterpret_cast<const f16x8*>(
                    Hc + r * 512 + (cbyte ^ ((r & 7) << 4)));
            }
#pragma unroll
            for (int nt = 0; nt < 2; ++nt)
#pragma unroll
                for (int et = 0; et < 2; ++et)
                    acc[nt][et] = __builtin_amdgcn_mfma_f32_16x16x32_f16(hfrag[nt], wB[et][ks], acc[nt][et], 0, 0, 0);
            if (t > 0) {
                f16x8 sfrag[2];
#pragma unroll
                for (int nt = 0; nt < 2; ++nt) {
                    int r = nt * 16 + lr;
                    sfrag[nt] = *reinterpret_cast<const f16x8*>(
                        Sc + r * 512 + (cbyte ^ ((r & 7) << 4)));
                }
#pragma unroll
                for (int nt = 0; nt < 2; ++nt)
#pragma unroll
                    for (int et = 0; et < 2; ++et)
                        acc[nt][et] = __builtin_amdgcn_mfma_f32_16x16x32_f16(sfrag[nt], wA[et][ks], acc[nt][et], 0, 0, 0);
            }
        }
        __builtin_amdgcn_s_setprio(0);

        // 3a. STAGE H_{t+1} (in hreg since the PREVIOUS step -> its vmcnt is
        //     long satisfied; no load stall here) into Hn.
        if (t + 1 < T_STEPS) {
#pragma unroll
            for (int j = 0; j < 3; ++j) {
                int idx = j * 512 + tid;
                if (idx < NCHUNK4) {
                    int r = idx >> 6;
                    f16x4 v;
#pragma unroll
                    for (int k = 0; k < 4; ++k) v[k] = (_Float16)hreg[j][k];
                    *reinterpret_cast<f16x4*>(Hn + r * 512 + (((idx & 63) * 8) ^ ((r & 7) << 4))) = v;
                }
            }
        }

        // 3b. immediately re-ISSUE the bank with H_{t+2}: a FULL step of
        //     latency cover before its STAGE at step t+1.
        if (t + 2 < T_STEPS) {
            const float* Ht2 = Hslab + (size_t)(t + 2) * NROWS * DDIM;
#pragma unroll
            for (int j = 0; j < 3; ++j) {
                int idx = j * 512 + tid;
                if (idx < NCHUNK4)
                    hreg[j] = __builtin_nontemporal_load(
                        reinterpret_cast<const f32x4*>(Ht2 + (size_t)idx * 4));
            }
        }

        // 4. S_t -> Sn (f16, swizzled). Rows 20-31 are pad (never stored).
#pragma unroll
        for (int nt = 0; nt < 2; ++nt) {
#pragma unroll
            for (int et = 0; et < 2; ++et) {
                const int c = wc * 32 + et * 16 + lr;
#pragma unroll
                for (int i = 0; i < 4; ++i) {
                    int r = nt * 16 + kg * 4 + i;
                    *reinterpret_cast<_Float16*>(Sn + r * 512 + ((c * 2) ^ ((r & 7) << 4))) =
                        (_Float16)acc[nt][et][i];
                }
            }
        }

        // 5. single lgkm-only barrier: Sn/Hn complete & visible; global
        //    stores and the H_{t+2} loads keep flying in the background.
        barrier_lgkm();

        // 6. epilogue: row-contiguous readback of Sn -> coalesced NT f32
        //    stores. 640 chunks of 16B (20 real rows x 32 chunks/row).
        float* Ot = out + (size_t)t * NROWS * DDIM;
#pragma unroll
        for (int p = 0; p < 2; ++p) {
            int idx = p * 512 + tid;
            if (idx < NCHUNK16) {
                int r   = idx >> 5;                // 0..19 (real rows only)
                int c16 = idx & 31;                // 16B chunk within row
                f16x8 v = *reinterpret_cast<const f16x8*>(
                    Sn + r * 512 + ((c16 * 16) ^ ((r & 7) << 4)));
                int gr = row0 + r;
                f32x4 lo, hi;
#pragma unroll
                for (int k = 0; k < 4; ++k) { lo[k] = (float)v[k]; hi[k] = (float)v[k + 4]; }
                float* dst = Ot + (size_t)gr * DDIM + c16 * 8;
                __builtin_nontemporal_store(lo, reinterpret_cast<f32x4*>(dst));
                __builtin_nontemporal_store(hi, reinterpret_cast<f32x4*>(dst + 4));
            }
        }
        // no second barrier: next step's LDS writes target the opposite
        // buffers; this epilogue's reads complete before this wave's next
        // lgkmcnt(0)+barrier, which precedes any conflicting write (t+2).
    }
}

extern "C" void kernel_launch(void* const* d_in, const int* in_sizes, int n_in,
                              void* d_out, int out_size, void* d_ws, size_t ws_size,
                              hipStream_t stream)
{
    const float* H  = (const float*)d_in[0];
    const float* Aw = (const float*)d_in[1];
    const float* Bw = (const float*)d_in[2];
    const float* Bb = (const float*)d_in[3];
    float* out      = (float*)d_out;

    _Float16* wsA = (_Float16*)d_ws;         // 128 KiB
    _Float16* wsB = wsA + 65536;             // 128 KiB

    cvt_weights_kernel<<<32, 256, 0, stream>>>(Aw, Bw, wsA, wsB);

    int nblocks = NROWS / ROWS_PB;           // 500 (10000/20, exact) -> 2/CU
    ssm_fused_kernel<<<nblocks, 512, 0, stream>>>(H, wsA, wsB, Bb, out);
}

// Round 15
// 134.763 us; speedup vs baseline: 1.1810x; 1.1810x over previous
//
#include <hip/hip_runtime.h>
#include <hip/hip_fp16.h>

typedef _Float16 f16x8 __attribute__((ext_vector_type(8)));
typedef _Float16 f16x4 __attribute__((ext_vector_type(4)));
typedef float    f32x4 __attribute__((ext_vector_type(4)));

#define T_STEPS 32
#define NROWS   10000
#define DDIM    256
#define ROWS_PB 40                     // 250 blocks exactly (10000/40), no tail
#define TILE_ROWS 48                   // LDS tile rows (40 real + 8 pad)
#define TILE_B  (TILE_ROWS * 512)      // 24576 B per f16 tile
#define NCHUNK16 (ROWS_PB * 32)        // 1280 16B chunks per S tile (real rows)

// ---------------------------------------------------------------------------
// Pre-kernel: f32 weights -> f16 MFMA B-fragments.
// Fragment (ct,ks), ct=0..15, ks=0..7:
//   dst[((ct*8+ks)*64+lane)*8 + j] = W[ct*16 + (lane&15)][ks*32 + (lane>>4)*8 + j]
// ---------------------------------------------------------------------------
__global__ __launch_bounds__(256) void cvt_weights_kernel(
    const float* __restrict__ Aw, const float* __restrict__ Bw,
    _Float16* __restrict__ wsA, _Float16* __restrict__ wsB)
{
    int tid  = blockIdx.x * 256 + threadIdx.x;      // 0..8191
    int lane = tid & 63;
    int ks   = (tid >> 6) & 7;
    int ct   = tid >> 9;                            // 0..15
    int e     = ct * 16 + (lane & 15);
    int dbase = ks * 32 + (lane >> 4) * 8;
    size_t src = (size_t)e * DDIM + dbase;
    size_t dst = (size_t)tid * 8;
#pragma unroll
    for (int j = 0; j < 8; ++j) {
        wsA[dst + j] = (_Float16)Aw[src + j];
        wsB[dst + j] = (_Float16)Bw[src + j];
    }
}

// Barrier WITHOUT the compiler's vmcnt(0) drain: LDS deps are covered by
// lgkmcnt(0); global stores / prefetch loads keep draining across steps.
__device__ __forceinline__ void barrier_lgkm() {
    asm volatile("s_waitcnt lgkmcnt(0)\n\ts_barrier" ::: "memory");
}

// ---------------------------------------------------------------------------
// Fused SSM, A-fragment-reuse + full-step H prefetch (R11 winner) +
// NON-TEMPORAL hints on the stream-once traffic (H loads, out stores) so
// the read/write streams don't thrash L2 against each other.
// Block = 40 rows x 32 steps. 8 waves (512 thr); wave w owns cols
// [32w,32w+32) = 2 col-tiles. Weights in registers (128 VGPR/lane).
// hreg bank: STAGE H_{t+1} (loaded a FULL step ago) right after the K-loop,
// then immediately re-ISSUE the bank with H_{t+2}. Double-buffered LDS
// H + S tiles, ONE lgkm-only barrier per step, full-128B-line f32 stores
// from LDS readback.
// ---------------------------------------------------------------------------
__global__ __launch_bounds__(512, 2) void ssm_fused_kernel(
    const float* __restrict__ H,          // [T][N][D] f32
    const _Float16* __restrict__ WaF,     // frag-permuted f16
    const _Float16* __restrict__ WbF,
    const float* __restrict__ bias,       // [D] f32
    float* __restrict__ out)              // [T][N][D] f32
{
    // Hbuf0 | Hbuf1 | Sbuf0 | Sbuf1, each 24 KiB (96 KiB total)
    __shared__ char lds[4 * TILE_B];

    const int tid  = threadIdx.x;
    const int lane = tid & 63;
    const int wc   = tid >> 6;            // 0..7: 32-col strip
    const int lr   = lane & 15;
    const int kg   = lane >> 4;           // 0..3
    const int row0 = blockIdx.x * ROWS_PB;

    // ---- one-time: this wave's weight fragments (2 col-tiles) -> 128 VGPRs
    f16x8 wA[2][8], wB[2][8];
#pragma unroll
    for (int et = 0; et < 2; ++et) {
        const int ct = wc * 2 + et;
#pragma unroll
        for (int ks = 0; ks < 8; ++ks) {
            size_t o = (size_t)((ct * 8 + ks) * 64 + lane) * 8;
            wA[et][ks] = *reinterpret_cast<const f16x8*>(WaF + o);
            wB[et][ks] = *reinterpret_cast<const f16x8*>(WbF + o);
        }
    }

    float bv[2];
#pragma unroll
    for (int et = 0; et < 2; ++et) bv[et] = bias[wc * 32 + et * 16 + lr];

    // Block's H slab at step t: H + t*N*D + row0*D, 10240 floats, contiguous.
    const float* Hslab = H + (size_t)row0 * DDIM;

    // ---- prologue: H_0 -> Hbuf0, then issue H_1 into the (single) bank ----
    f32x4 hreg[5];
#pragma unroll
    for (int j = 0; j < 5; ++j) {
        int idx = j * 512 + tid;
        hreg[j] = __builtin_nontemporal_load(
            reinterpret_cast<const f32x4*>(Hslab + (size_t)idx * 4));
    }
#pragma unroll
    for (int j = 0; j < 5; ++j) {
        int idx = j * 512 + tid;
        int r = idx >> 6;
        f16x4 v;
#pragma unroll
        for (int k = 0; k < 4; ++k) v[k] = (_Float16)hreg[j][k];
        *reinterpret_cast<f16x4*>(lds + r * 512 + (((idx & 63) * 8) ^ ((r & 7) << 4))) = v;
    }
#pragma unroll
    for (int j = 0; j < 5; ++j) {
        int idx = j * 512 + tid;
        hreg[j] = __builtin_nontemporal_load(
            reinterpret_cast<const f32x4*>(Hslab + (size_t)NROWS * DDIM + (size_t)idx * 4));
    }
    __syncthreads();

    f32x4 acc[3][2];

    for (int t = 0; t < T_STEPS; ++t) {
        const int cur = t & 1;
        char* Hc = lds + cur * TILE_B;
        char* Hn = lds + (cur ^ 1) * TILE_B;
        char* Sc = lds + 2 * TILE_B + cur * TILE_B;
        char* Sn = lds + 2 * TILE_B + (cur ^ 1) * TILE_B;

        // 1. init acc with bias (C/D: col = lane&15)
#pragma unroll
        for (int nt = 0; nt < 3; ++nt)
#pragma unroll
            for (int et = 0; et < 2; ++et)
#pragma unroll
                for (int i = 0; i < 4; ++i) acc[nt][et][i] = bv[et];

        // 2. K-loop: each A-fragment read feeds BOTH col-tiles (2 MFMAs).
        __builtin_amdgcn_s_setprio(1);
#pragma unroll
        for (int ks = 0; ks < 8; ++ks) {
            const int cbyte = ks * 64 + kg * 16;
            f16x8 hfrag[3];
#pragma unroll
            for (int nt = 0; nt < 3; ++nt) {
                int r = nt * 16 + lr;
                hfrag[nt] = *reinterpret_cast<const f16x8*>(
                    Hc + r * 512 + (cbyte ^ ((r & 7) << 4)));
            }
#pragma unroll
            for (int nt = 0; nt < 3; ++nt)
#pragma unroll
                for (int et = 0; et < 2; ++et)
                    acc[nt][et] = __builtin_amdgcn_mfma_f32_16x16x32_f16(hfrag[nt], wB[et][ks], acc[nt][et], 0, 0, 0);
            if (t > 0) {
                f16x8 sfrag[3];
#pragma unroll
                for (int nt = 0; nt < 3; ++nt) {
                    int r = nt * 16 + lr;
                    sfrag[nt] = *reinterpret_cast<const f16x8*>(
                        Sc + r * 512 + (cbyte ^ ((r & 7) << 4)));
                }
#pragma unroll
                for (int nt = 0; nt < 3; ++nt)
#pragma unroll
                    for (int et = 0; et < 2; ++et)
                        acc[nt][et] = __builtin_amdgcn_mfma_f32_16x16x32_f16(sfrag[nt], wA[et][ks], acc[nt][et], 0, 0, 0);
            }
        }
        __builtin_amdgcn_s_setprio(0);

        // 3a. STAGE H_{t+1} (in hreg since the PREVIOUS step -> its vmcnt is
        //     long satisfied; no load stall here) into Hn.
        if (t + 1 < T_STEPS) {
#pragma unroll
            for (int j = 0; j < 5; ++j) {
                int idx = j * 512 + tid;
                int r = idx >> 6;
                f16x4 v;
#pragma unroll
                for (int k = 0; k < 4; ++k) v[k] = (_Float16)hreg[j][k];
                *reinterpret_cast<f16x4*>(Hn + r * 512 + (((idx & 63) * 8) ^ ((r & 7) << 4))) = v;
            }
        }

        // 3b. immediately re-ISSUE the bank with H_{t+2}: a FULL step of
        //     latency cover before its STAGE at step t+1.
        if (t + 2 < T_STEPS) {
            const float* Ht2 = Hslab + (size_t)(t + 2) * NROWS * DDIM;
#pragma unroll
            for (int j = 0; j < 5; ++j) {
                int idx = j * 512 + tid;
                hreg[j] = __builtin_nontemporal_load(
                    reinterpret_cast<const f32x4*>(Ht2 + (size_t)idx * 4));
            }
        }

        // 4. S_t -> Sn (f16, swizzled). Rows 40-47 are pad (never stored).
#pragma unroll
        for (int nt = 0; nt < 3; ++nt) {
#pragma unroll
            for (int et = 0; et < 2; ++et) {
                const int c = wc * 32 + et * 16 + lr;
#pragma unroll
                for (int i = 0; i < 4; ++i) {
                    int r = nt * 16 + kg * 4 + i;
                    *reinterpret_cast<_Float16*>(Sn + r * 512 + ((c * 2) ^ ((r & 7) << 4))) =
                        (_Float16)acc[nt][et][i];
                }
            }
        }

        // 5. single lgkm-only barrier: Sn/Hn complete & visible; global
        //    stores and the H_{t+2} loads keep flying in the background.
        barrier_lgkm();

        // 6. epilogue: row-contiguous readback of Sn -> coalesced NT f32
        //    stores. 1280 chunks of 16B (40 real rows x 32 chunks/row).
        float* Ot = out + (size_t)t * NROWS * DDIM;
#pragma unroll
        for (int p = 0; p < 3; ++p) {
            int idx = p * 512 + tid;
            if (idx < NCHUNK16) {
                int r   = idx >> 5;                // 0..39 (real rows only)
                int c16 = idx & 31;                // 16B chunk within row
                f16x8 v = *reinterpret_cast<const f16x8*>(
                    Sn + r * 512 + ((c16 * 16) ^ ((r & 7) << 4)));
                int gr = row0 + r;
                f32x4 lo, hi;
#pragma unroll
                for (int k = 0; k < 4; ++k) { lo[k] = (float)v[k]; hi[k] = (float)v[k + 4]; }
                float* dst = Ot + (size_t)gr * DDIM + c16 * 8;
                __builtin_nontemporal_store(lo, reinterpret_cast<f32x4*>(dst));
                __builtin_nontemporal_store(hi, reinterpret_cast<f32x4*>(dst + 4));
            }
        }
        // no second barrier: next step's LDS writes target the opposite
        // buffers; this epilogue's reads complete before this wave's next
        // lgkmcnt(0)+barrier, which precedes any conflicting write (t+2).
    }
}

extern "C" void kernel_launch(void* const* d_in, const int* in_sizes, int n_in,
                              void* d_out, int out_size, void* d_ws, size_t ws_size,
                              hipStream_t stream)
{
    const float* H  = (const float*)d_in[0];
    const float* Aw = (const float*)d_in[1];
    const float* Bw = (const float*)d_in[2];
    const float* Bb = (const float*)d_in[3];
    float* out      = (float*)d_out;

    _Float16* wsA = (_Float16*)d_ws;         // 128 KiB
    _Float16* wsB = wsA + 65536;             // 128 KiB

    cvt_weights_kernel<<<32, 256, 0, stream>>>(Aw, Bw, wsA, wsB);

    int nblocks = NROWS / ROWS_PB;           // 250 (10000/40, exact)
    ssm_fused_kernel<<<nblocks, 512, 0, stream>>>(H, wsA, wsB, Bb, out);
}